// Round 6
// baseline (714.146 us; speedup 1.0000x reference)
//
#include <hip/hip_runtime.h>
#include <hip/hip_bf16.h>
#include <math.h>

// Problem constants (B=4, S=4096 -> T=16384 tokens)
#define TOKENS 16384
#define HD 1024
#define FD 2048
#define NEXP 8
#define MAX_MT 136            // max 256-row m-tiles: 32768/256 + 8 partials (div by 8)
#define RP_MAX (MAX_MT * 256) // 34816 padded routed rows
#define NTN1 16               // gemm1 n-tiles: FD/128
#define NTN2 8                // gemm2 n-tiles: HD/128

typedef __bf16 bf16x8 __attribute__((ext_vector_type(8)));
typedef float f32x4 __attribute__((ext_vector_type(4)));
typedef unsigned short u16;
typedef unsigned int u32;

__device__ __forceinline__ u16 f2bf(float f) {
    union { float f; u32 u; } v; v.f = f;
    return (u16)((v.u + 0x7FFFu + ((v.u >> 16) & 1u)) >> 16);
}

#define GLOAD16(g, l) __builtin_amdgcn_global_load_lds( \
    (const __attribute__((address_space(1))) u32*)(g),  \
    (__attribute__((address_space(3))) u32*)(l), 16, 0, 0)

// ---------------- routing ----------------

__global__ void init_routing(int* sorted_rid, int* counts, int* fill, int* numTiles) {
    int i = blockIdx.x * blockDim.x + threadIdx.x;
    if (i < RP_MAX) sorted_rid[i] = -1;
    if (i < NEXP) { counts[i] = 0; fill[i] = 0; }
    if (i == 0) *numTiles = 0;
}

__global__ void count_kernel(const int* __restrict__ te, int* counts) {
    int j = blockIdx.x * blockDim.x + threadIdx.x;
    if (j < TOKENS * 2) atomicAdd(&counts[te[j]], 1);
}

__global__ void scan_kernel(const int* __restrict__ counts, int* offs,
                            int* tileE, int* tileRow, int* numTiles) {
    if (blockIdx.x == 0 && threadIdx.x == 0) {
        int o = 0, t = 0;
        for (int e = 0; e < NEXP; e++) {
            offs[e] = o;
            int nt = (counts[e] + 255) >> 8;
            for (int i = 0; i < nt; i++) { tileE[t] = e; tileRow[t] = o + i * 256; t++; }
            o += nt * 256;
        }
        *numTiles = t;
    }
}

// scatter + inverse map (rid -> padded slot) for the non-atomic combine
__global__ void scatter_kernel(const int* __restrict__ te, const int* __restrict__ offs,
                               int* fill, int* sorted_rid, int* inv) {
    int j = blockIdx.x * blockDim.x + threadIdx.x;
    if (j < TOKENS * 2) {
        int e = te[j];
        int p = offs[e] + atomicAdd(&fill[e], 1);
        sorted_rid[p] = j;
        inv[j] = p;
    }
}

// ---------------- conversions ----------------

__global__ void convert_x(const float* __restrict__ x, u16* __restrict__ xb) {
    int i = blockIdx.x * blockDim.x + threadIdx.x;   // one thread = 8 elems
    const float4* xv = (const float4*)x;
    float4 a = xv[i * 2], b = xv[i * 2 + 1];
    union { u16 s[8]; uint4 v; } o;
    o.s[0] = f2bf(a.x); o.s[1] = f2bf(a.y); o.s[2] = f2bf(a.z); o.s[3] = f2bf(a.w);
    o.s[4] = f2bf(b.x); o.s[5] = f2bf(b.y); o.s[6] = f2bf(b.z); o.s[7] = f2bf(b.w);
    *(uint4*)(xb + (size_t)i * 8) = o.v;
}

// in: [E][K][N] f32  ->  out: [E][N][K] bf16
__global__ void transpose_conv(const float* __restrict__ in, u16* __restrict__ out,
                               int K, int N) {
    __shared__ float tile[32][33];
    int e = blockIdx.z;
    int n0 = blockIdx.x * 32, k0 = blockIdx.y * 32;
    const float* src = in + (size_t)e * K * N;
    u16* dst = out + (size_t)e * N * K;
    int tx = threadIdx.x, ty = threadIdx.y;
    #pragma unroll
    for (int j = 0; j < 32; j += 8)
        tile[ty + j][tx] = src[(size_t)(k0 + ty + j) * N + n0 + tx];
    __syncthreads();
    #pragma unroll
    for (int j = 0; j < 32; j += 8)
        dst[(size_t)(n0 + ty + j) * K + k0 + tx] = f2bf(tile[tx][ty + j]);
}

// ==================================================================
// 256x128 grouped-GEMM core: BK=64, 512 threads (8 waves, 4M x 2N,
// per-wave 64x64 out). 3-deep LDS ring (A 3x32KB + B 3x16KB = 144KB):
// K-tile t computes from buf t%3 while staging t+2 into (t+2)%3 —
// staged buffer is NEVER the read buffer (race-free by construction).
// In-loop wait is counted vmcnt(6) (= next tile's 6 loads), never 0
// until the tail (T4). One s_barrier per K-tile. T2 XOR swizzle via
// pre-swizzled global source (proven 0 conflicts). T5 setprio on MFMA.
// ==================================================================

// ---------------- grouped GEMM 1: H_act = gelu(X[gather] @ w1 + b1) ----------------

__global__ __launch_bounds__(512, 2) void gemm1_kernel(
    const u16* __restrict__ Xb, const u16* __restrict__ W1t,
    const float* __restrict__ b1, const int* __restrict__ sorted_rid,
    const int* __restrict__ tileE, const int* __restrict__ tileRow,
    const int* __restrict__ numTiles, u16* __restrict__ Hact)
{
    // XCD-bijective decode (MAX_MT divisible by 8)
    int bid = blockIdx.x;
    int xcd = bid & 7, slot = bid >> 3;
    int mt = xcd + (slot / NTN1) * 8;
    int n0 = (slot % NTN1) * 128;
    if (mt >= *numTiles) return;
    int e = tileE[mt];
    int row0 = tileRow[mt];

    __shared__ __align__(16) u16 As[3][256 * 64];   // 3 x 32 KB
    __shared__ __align__(16) u16 Bs[3][128 * 64];   // 3 x 16 KB
    char* AsB = (char*)&As[0][0];
    char* BsB = (char*)&Bs[0][0];

    int tid = threadIdx.x;
    int wave = tid >> 6, lane = tid & 63;
    int laneR = lane & 15, kgrp = lane >> 4;
    int wr = wave >> 1, wc = wave & 1;

    // staging sources (pre-swizzled): A rows 0..255 (4 issues), B rows 0..127 (2)
    const u16* gA[4]; const u16* gB[2];
    #pragma unroll
    for (int i = 0; i < 4; i++) {
        int c = i * 512 + tid;
        int r = c >> 3, kc = c & 7;
        int kcs = kc ^ (r & 7);
        int rid = sorted_rid[row0 + r];
        int tok = rid < 0 ? 0 : (rid >> 1);
        gA[i] = Xb + (size_t)tok * HD + kcs * 8;
    }
    #pragma unroll
    for (int i = 0; i < 2; i++) {
        int c = i * 512 + tid;
        int r = c >> 3, kc = c & 7;
        int kcs = kc ^ (r & 7);
        gB[i] = W1t + ((size_t)e * FD + (n0 + r)) * HD + kcs * 8;
    }
    auto stage = [&](int t_) {
        int buf = t_ % 3;
        char* dA = AsB + buf * 32768 + tid * 16;
        char* dB = BsB + buf * 16384 + tid * 16;
        #pragma unroll
        for (int i = 0; i < 4; i++) GLOAD16(gA[i] + t_ * 64, dA + i * 8192);
        #pragma unroll
        for (int i = 0; i < 2; i++) GLOAD16(gB[i] + t_ * 64, dB + i * 8192);
    };

    // swizzled LDS read bases: row&7 == laneR&7
    int off0 = ((kgrp ^ (laneR & 7)) << 4);
    int off1 = off0 ^ 64;
    const int rowA = (wr * 64 + laneR) * 128;
    const int rowB = (wc * 64 + laneR) * 128;

    f32x4 acc[4][4] = {};
    const int NT = HD / 64;

    stage(0); stage(1);
    asm volatile("s_waitcnt vmcnt(6)" ::: "memory");   // tile 0 resident
    __builtin_amdgcn_s_barrier();
    __builtin_amdgcn_sched_barrier(0);

    for (int t = 0; t < NT; t++) {
        int buf = t % 3;
        const char* Ab = AsB + buf * 32768 + rowA;
        const char* Bb = BsB + buf * 16384 + rowB;
        bf16x8 a[4][2], b[4][2];
        #pragma unroll
        for (int mf = 0; mf < 4; mf++) {
            a[mf][0] = *(const bf16x8*)(Ab + mf * 2048 + off0);
            a[mf][1] = *(const bf16x8*)(Ab + mf * 2048 + off1);
        }
        #pragma unroll
        for (int nf = 0; nf < 4; nf++) {
            b[nf][0] = *(const bf16x8*)(Bb + nf * 2048 + off0);
            b[nf][1] = *(const bf16x8*)(Bb + nf * 2048 + off1);
        }
        if (t + 2 < NT) stage(t + 2);                  // into buf (t+2)%3, disjoint
        __builtin_amdgcn_sched_barrier(0);
        __builtin_amdgcn_s_setprio(1);
        #pragma unroll
        for (int kk = 0; kk < 2; kk++)
            #pragma unroll
            for (int mf = 0; mf < 4; mf++)
                #pragma unroll
                for (int nf = 0; nf < 4; nf++)
                    acc[mf][nf] = __builtin_amdgcn_mfma_f32_16x16x32_bf16(
                        a[mf][kk], b[nf][kk], acc[mf][nf], 0, 0, 0);
        __builtin_amdgcn_s_setprio(0);
        if (t < NT - 1) {
            if (t < NT - 2) { asm volatile("s_waitcnt vmcnt(6)" ::: "memory"); }
            else            { asm volatile("s_waitcnt vmcnt(0)" ::: "memory"); }
            __builtin_amdgcn_s_barrier();
            __builtin_amdgcn_sched_barrier(0);
        }
    }

    // epilogue: bias + tanh-form gelu (abs err <= ~1e-3 << bf16 quantum)
    const float* b1e = b1 + e * FD + n0;
    #pragma unroll
    for (int nf = 0; nf < 4; nf++) {
        int col = wc * 64 + nf * 16 + laneR;
        float bias = b1e[col];
        #pragma unroll
        for (int mf = 0; mf < 4; mf++) {
            int rbase = row0 + wr * 64 + mf * 16 + kgrp * 4;
            #pragma unroll
            for (int r = 0; r < 4; r++) {
                float v = acc[mf][nf][r] + bias;
                float g = v / (1.0f + __expf(-1.5957692f * (v + 0.044715f * v * v * v)));
                Hact[(size_t)(rbase + r) * FD + n0 + col] = f2bf(g);
            }
        }
    }
}

// ---------------- grouped GEMM 2: Out2[slot] = H_act @ w2 + b2 (bf16) ----------------

__global__ __launch_bounds__(512, 2) void gemm2_kernel(
    const u16* __restrict__ Hact, const u16* __restrict__ W2t,
    const float* __restrict__ b2,
    const int* __restrict__ tileE, const int* __restrict__ tileRow,
    const int* __restrict__ numTiles, u16* __restrict__ Out2)
{
    int bid = blockIdx.x;
    int xcd = bid & 7, slot = bid >> 3;
    int mt = xcd + (slot / NTN2) * 8;
    int n0 = (slot % NTN2) * 128;
    if (mt >= *numTiles) return;
    int e = tileE[mt];
    int row0 = tileRow[mt];

    __shared__ __align__(16) u16 As[3][256 * 64];
    __shared__ __align__(16) u16 Bs[3][128 * 64];
    char* AsB = (char*)&As[0][0];
    char* BsB = (char*)&Bs[0][0];

    int tid = threadIdx.x;
    int wave = tid >> 6, lane = tid & 63;
    int laneR = lane & 15, kgrp = lane >> 4;
    int wr = wave >> 1, wc = wave & 1;

    const u16* gA[4]; const u16* gB[2];
    #pragma unroll
    for (int i = 0; i < 4; i++) {
        int c = i * 512 + tid;
        int r = c >> 3, kc = c & 7;
        int kcs = kc ^ (r & 7);
        gA[i] = Hact + (size_t)(row0 + r) * FD + kcs * 8;
    }
    #pragma unroll
    for (int i = 0; i < 2; i++) {
        int c = i * 512 + tid;
        int r = c >> 3, kc = c & 7;
        int kcs = kc ^ (r & 7);
        gB[i] = W2t + ((size_t)e * HD + (n0 + r)) * FD + kcs * 8;
    }
    auto stage = [&](int t_) {
        int buf = t_ % 3;
        char* dA = AsB + buf * 32768 + tid * 16;
        char* dB = BsB + buf * 16384 + tid * 16;
        #pragma unroll
        for (int i = 0; i < 4; i++) GLOAD16(gA[i] + t_ * 64, dA + i * 8192);
        #pragma unroll
        for (int i = 0; i < 2; i++) GLOAD16(gB[i] + t_ * 64, dB + i * 8192);
    };

    int off0 = ((kgrp ^ (laneR & 7)) << 4);
    int off1 = off0 ^ 64;
    const int rowA = (wr * 64 + laneR) * 128;
    const int rowB = (wc * 64 + laneR) * 128;

    f32x4 acc[4][4] = {};
    const int NT = FD / 64;

    stage(0); stage(1);
    asm volatile("s_waitcnt vmcnt(6)" ::: "memory");
    __builtin_amdgcn_s_barrier();
    __builtin_amdgcn_sched_barrier(0);

    for (int t = 0; t < NT; t++) {
        int buf = t % 3;
        const char* Ab = AsB + buf * 32768 + rowA;
        const char* Bb = BsB + buf * 16384 + rowB;
        bf16x8 a[4][2], b[4][2];
        #pragma unroll
        for (int mf = 0; mf < 4; mf++) {
            a[mf][0] = *(const bf16x8*)(Ab + mf * 2048 + off0);
            a[mf][1] = *(const bf16x8*)(Ab + mf * 2048 + off1);
        }
        #pragma unroll
        for (int nf = 0; nf < 4; nf++) {
            b[nf][0] = *(const bf16x8*)(Bb + nf * 2048 + off0);
            b[nf][1] = *(const bf16x8*)(Bb + nf * 2048 + off1);
        }
        if (t + 2 < NT) stage(t + 2);
        __builtin_amdgcn_sched_barrier(0);
        __builtin_amdgcn_s_setprio(1);
        #pragma unroll
        for (int kk = 0; kk < 2; kk++)
            #pragma unroll
            for (int mf = 0; mf < 4; mf++)
                #pragma unroll
                for (int nf = 0; nf < 4; nf++)
                    acc[mf][nf] = __builtin_amdgcn_mfma_f32_16x16x32_bf16(
                        a[mf][kk], b[nf][kk], acc[mf][nf], 0, 0, 0);
        __builtin_amdgcn_s_setprio(0);
        if (t < NT - 1) {
            if (t < NT - 2) { asm volatile("s_waitcnt vmcnt(6)" ::: "memory"); }
            else            { asm volatile("s_waitcnt vmcnt(0)" ::: "memory"); }
            __builtin_amdgcn_s_barrier();
            __builtin_amdgcn_sched_barrier(0);
        }
    }

    // epilogue: bias -> plain bf16 store into slot-major Out2 (no atomics)
    const float* b2e = b2 + e * HD + n0;
    #pragma unroll
    for (int mf = 0; mf < 4; mf++) {
        int rbase = row0 + wr * 64 + mf * 16 + kgrp * 4;
        #pragma unroll
        for (int r = 0; r < 4; r++) {
            u16* orow = Out2 + (size_t)(rbase + r) * HD + n0;
            #pragma unroll
            for (int nf = 0; nf < 4; nf++) {
                int col = wc * 64 + nf * 16 + laneR;
                orow[col] = f2bf(acc[mf][nf][r] + b2e[col]);
            }
        }
    }
}

// ---------------- combine: y[t] = w0*Out2[inv[2t]] + w1*Out2[inv[2t+1]] ----------------

__global__ void combine_kernel(const u16* __restrict__ Out2, const int* __restrict__ inv,
                               const float* __restrict__ ew, float* __restrict__ y) {
    int i = blockIdx.x * blockDim.x + threadIdx.x;   // one thread = 8 cols of one token
    int tok = i >> 7;
    int c0 = (i & 127) << 3;
    int s0 = inv[2 * tok], s1 = inv[2 * tok + 1];
    float w0 = ew[2 * tok], w1 = ew[2 * tok + 1];
    union { uint4 v; u16 s[8]; } a, b;
    a.v = *(const uint4*)(Out2 + (size_t)s0 * HD + c0);
    b.v = *(const uint4*)(Out2 + (size_t)s1 * HD + c0);
    float out[8];
    #pragma unroll
    for (int j = 0; j < 8; j++) {
        union { u32 u; float f; } fa, fb;
        fa.u = (u32)a.s[j] << 16;
        fb.u = (u32)b.s[j] << 16;
        out[j] = w0 * fa.f + w1 * fb.f;
    }
    float4* yp = (float4*)(y + (size_t)tok * HD + c0);
    yp[0] = *(const float4*)&out[0];
    yp[1] = *(const float4*)&out[4];
}

// ---------------- launch ----------------

extern "C" void kernel_launch(void* const* d_in, const int* in_sizes, int n_in,
                              void* d_out, int out_size, void* d_ws, size_t ws_size,
                              hipStream_t stream) {
    const float* x  = (const float*)d_in[0];
    const float* ew = (const float*)d_in[1];
    const int*   te = (const int*)d_in[2];
    const float* w1 = (const float*)d_in[3];
    const float* b1 = (const float*)d_in[4];
    const float* w2 = (const float*)d_in[5];
    const float* b2 = (const float*)d_in[6];
    float* y = (float*)d_out;

    char* ws = (char*)d_ws;
    // layout: Xb[0,32M) W1t[32M,64M) | W2t[68M,100M) Hact[100M,236M) ;
    // Out2[0,68M) overlays Xb+W1t (both dead before gemm2 writes Out2).
    u16* Xb   = (u16*)(ws);                      // 33,554,432 B
    u16* W1t  = (u16*)(ws + 33554432);           // 33,554,432 B
    u16* Out2 = (u16*)(ws);                      // 71,303,168 B (RP_MAX x 1024 bf16)
    u16* W2t  = (u16*)(ws + 71303168);           // 33,554,432 B
    u16* Hact = (u16*)(ws + 104857600);          // 142,606,336 B (RP_MAX x 2048 bf16)
    char* ip  = ws + 247463936;
    int* counts   = (int*)(ip);
    int* fill     = (int*)(ip + 32);
    int* offs     = (int*)(ip + 64);
    int* numTiles = (int*)(ip + 96);
    int* tileE    = (int*)(ip + 128);            // 544 B
    int* tileRow  = (int*)(ip + 1024);           // 544 B
    int* sorted   = (int*)(ip + 4096);           // 139,264 B
    int* inv      = (int*)(ip + 143360);         // 131,072 B

    // routing
    init_routing<<<(RP_MAX + 255) / 256, 256, 0, stream>>>(sorted, counts, fill, numTiles);
    count_kernel<<<(TOKENS * 2 + 255) / 256, 256, 0, stream>>>(te, counts);
    scan_kernel<<<1, 64, 0, stream>>>(counts, offs, tileE, tileRow, numTiles);
    scatter_kernel<<<(TOKENS * 2 + 255) / 256, 256, 0, stream>>>(te, offs, fill, sorted, inv);

    // conversions needed by gemm1
    convert_x<<<(TOKENS * HD / 8 + 255) / 256, 256, 0, stream>>>(x, Xb);
    transpose_conv<<<dim3(FD / 32, HD / 32, NEXP), dim3(32, 8), 0, stream>>>(w1, W1t, HD, FD);

    // w2 transpose (region disjoint from Xb/W1t/Hact)
    transpose_conv<<<dim3(HD / 32, FD / 32, NEXP), dim3(32, 8), 0, stream>>>(w2, W2t, FD, HD);

    // grouped GEMM 1
    gemm1_kernel<<<(MAX_MT / 8) * NTN1 * 8, 512, 0, stream>>>(
        Xb, W1t, b1, sorted, tileE, tileRow, numTiles, Hact);

    // grouped GEMM 2 (plain stores; Out2 overlays dead Xb/W1t)
    gemm2_kernel<<<(MAX_MT / 8) * NTN2 * 8, 512, 0, stream>>>(
        Hact, W2t, b2, tileE, tileRow, numTiles, Out2);

    // weighted topk combine
    combine_kernel<<<(TOKENS * 128) / 256, 256, 0, stream>>>(Out2, inv, ew, y);
}

// Round 7
// 488.504 us; speedup vs baseline: 1.4619x; 1.4619x over previous
//
#include <hip/hip_runtime.h>
#include <hip/hip_bf16.h>
#include <math.h>

// Problem constants (B=4, S=4096 -> T=16384 tokens)
#define TOKENS 16384
#define HD 1024
#define FD 2048
#define NEXP 8
#define RP_MAX (264 * 128)   // max padded routed rows
#define MAX_MT 264           // max 128-row m-tiles (divisible by 8 for XCD swizzle)
#define NTN1 16              // gemm1 n-tiles: FD/128
#define NTN2 8               // gemm2 n-tiles: HD/128

// mega-prep block ranges (1024 threads/block)
#define NB_CONV 2048         // convert_x: 2,097,152 threads
#define NB_W1   16384        // w1 transpose tiles (64 x 32 x 8)
#define NB_W2   16384        // w2 transpose tiles (32 x 64 x 8)
#define NB_PREP (NB_CONV + NB_W1 + NB_W2 + 1)   // +1 routing block

typedef __bf16 bf16x8 __attribute__((ext_vector_type(8)));
typedef float f32x4 __attribute__((ext_vector_type(4)));
typedef unsigned short u16;
typedef unsigned int u32;

__device__ __forceinline__ u16 f2bf(float f) {
    union { float f; u32 u; } v; v.f = f;
    return (u16)((v.u + 0x7FFFu + ((v.u >> 16) & 1u)) >> 16);
}

#define GLOAD16(g, l) __builtin_amdgcn_global_load_lds( \
    (const __attribute__((address_space(1))) u32*)(g),  \
    (__attribute__((address_space(3))) u32*)(l), 16, 0, 0)

// ==================================================================
// mega-prep: convert_x | w1 transpose | w2 transpose | routing
// all independent; routing is the single last block (hides under prep)
// ==================================================================
__global__ __launch_bounds__(1024) void mega_prep(
    const float* __restrict__ x, u16* __restrict__ xb,
    const float* __restrict__ w1, u16* __restrict__ w1t,
    const float* __restrict__ w2, u16* __restrict__ w2t,
    const int* __restrict__ te,
    int* sorted_rid, int* inv, int* tileE, int* tileRow,
    int* numTiles, int* padcum)
{
    __shared__ float tile[32][33];
    __shared__ int cntS[NEXP], offsS[NEXP], fillS[NEXP], padS[NEXP], ntS;
    int b = blockIdx.x;
    int tid = threadIdx.x;

    if (b < NB_CONV) {                       // ---- convert x -> bf16
        int i = b * 1024 + tid;              // one thread = 8 elems
        const float4* xv = (const float4*)x;
        float4 a = xv[i * 2], c = xv[i * 2 + 1];
        union { u16 s[8]; uint4 v; } o;
        o.s[0] = f2bf(a.x); o.s[1] = f2bf(a.y); o.s[2] = f2bf(a.z); o.s[3] = f2bf(a.w);
        o.s[4] = f2bf(c.x); o.s[5] = f2bf(c.y); o.s[6] = f2bf(c.z); o.s[7] = f2bf(c.w);
        *(uint4*)(xb + (size_t)i * 8) = o.v;
        return;
    }
    if (b < NB_CONV + NB_W1 + NB_W2) {       // ---- weight transpose [E][K][N]->[E][N][K]
        const float* src; u16* dst; int K, N, n0, k0, e;
        if (b < NB_CONV + NB_W1) {
            int bb = b - NB_CONV;
            e = bb >> 11; int r = bb & 2047;
            n0 = (r & 63) * 32; k0 = (r >> 6) * 32;
            K = HD; N = FD; src = w1; dst = w1t;
        } else {
            int bb = b - NB_CONV - NB_W1;
            e = bb >> 11; int r = bb & 2047;
            n0 = (r & 31) * 32; k0 = (r >> 5) * 32;
            K = FD; N = HD; src = w2; dst = w2t;
        }
        int tx = tid & 31, ty = tid >> 5;    // 32 x 32
        const float* s = src + (size_t)e * K * N;
        u16* d = dst + (size_t)e * N * K;
        tile[ty][tx] = s[(size_t)(k0 + ty) * N + n0 + tx];
        __syncthreads();
        d[(size_t)(n0 + ty) * K + k0 + tx] = f2bf(tile[tx][ty]);
        return;
    }

    // ---- routing (single block, 1024 threads = 16 waves)
    int lane = tid & 63;
    if (tid < NEXP) cntS[tid] = 0;
    __syncthreads();
    // pass 1: register histogram + wave reduce + LDS accumulate
    int h[NEXP] = {0, 0, 0, 0, 0, 0, 0, 0};
    for (int j = tid; j < TOKENS * 2; j += 1024) {
        int v = te[j];
        #pragma unroll
        for (int e = 0; e < NEXP; e++) h[e] += (v == e);
    }
    #pragma unroll
    for (int e = 0; e < NEXP; e++) {
        int s = h[e];
        #pragma unroll
        for (int o = 32; o > 0; o >>= 1) s += __shfl_down(s, o, 64);
        if (lane == 0 && s) atomicAdd(&cntS[e], s);
    }
    __syncthreads();
    if (tid == 0) {
        int o = 0, t = 0, pc = 0;
        for (int e = 0; e < NEXP; e++) {
            offsS[e] = o; fillS[e] = 0;
            int pad = o - pc;
            padS[e] = pad; padcum[e] = pad;
            int c = cntS[e];
            int nt = (c + 127) >> 7;
            for (int i = 0; i < nt; i++) { tileE[t] = e; tileRow[t] = o + i * 128; t++; }
            o += nt * 128; pc += c;
        }
        ntS = t;
        *numTiles = t;
    }
    __syncthreads();
    int tot = ntS * 128;
    for (int i = tid; i < tot; i += 1024) sorted_rid[i] = -1;
    __syncthreads();
    // pass 2: scatter via ballot-aggregated LDS atomics (order within expert free)
    for (int j = tid; j < TOKENS * 2; j += 1024) {   // 65536/1024: full waves always
        int v = te[j];
        int base = 0;
        #pragma unroll
        for (int e = 0; e < NEXP; e++) {
            unsigned long long m = __ballot(v == e);
            if (m) {
                int ldr = (int)__builtin_ctzll(m);
                int bb = 0;
                if (lane == ldr) bb = atomicAdd(&fillS[e], __popcll(m));
                bb = __shfl(bb, ldr, 64);
                if (v == e) base = bb + (int)__popcll(m & ((1ull << lane) - 1ull));
            }
        }
        int p = offsS[v] + base;
        sorted_rid[p] = j;
        inv[j] = p - padS[v];            // compacted (pad-free) slot
    }
}

// ==================================================================
// 128x128 grouped-GEMM core (round-5 proven, 745 TF): BK=64, 4 waves,
// single LDS buffer, stage -> sync -> 32 MFMA -> sync. T2 XOR swizzle
// via pre-swizzled global source (0 conflicts). T1 XCD-bijective grid.
// ==================================================================

// ---------------- grouped GEMM 1: H_act = gelu(X[gather] @ w1 + b1) ----------------

__global__ __launch_bounds__(256, 2) void gemm1_kernel(
    const u16* __restrict__ Xb, const u16* __restrict__ W1t,
    const float* __restrict__ b1, const int* __restrict__ sorted_rid,
    const int* __restrict__ tileE, const int* __restrict__ tileRow,
    const int* __restrict__ numTiles, u16* __restrict__ Hact)
{
    int bid = blockIdx.x;
    int xcd = bid & 7, slot = bid >> 3;
    int mt = xcd + (slot / NTN1) * 8;
    int n0 = (slot % NTN1) * 128;
    if (mt >= *numTiles) return;
    int e = tileE[mt];
    int row0 = tileRow[mt];

    __shared__ __align__(16) u16 As[128 * 64];
    __shared__ __align__(16) u16 Bs[128 * 64];

    int tid = threadIdx.x;
    int wave = tid >> 6, lane = tid & 63;
    int laneR = lane & 15;

    const u16* gA[4]; const u16* gB[4];
    #pragma unroll
    for (int i = 0; i < 4; i++) {
        int c = i * 256 + tid;
        int r = c >> 3, kc = c & 7;
        int kcs = kc ^ (r & 7);
        int rid = sorted_rid[row0 + r];
        int tok = rid < 0 ? 0 : (rid >> 1);
        gA[i] = Xb + (size_t)tok * HD + kcs * 8;
        gB[i] = W1t + ((size_t)e * FD + (n0 + r)) * HD + kcs * 8;
    }
    char* AsB = (char*)As; char* BsB = (char*)Bs;

    f32x4 acc[4][4] = {};

    int wr = wave >> 1, wc = wave & 1;
    int off0 = (((lane >> 4) ^ (lane & 7)) << 4);
    int off1 = off0 ^ 64;
    const char* Abase = AsB + (wr * 64 + laneR) * 128;
    const char* Bbase = BsB + (wc * 64 + laneR) * 128;

    for (int kt = 0; kt < HD / 64; kt++) {
        #pragma unroll
        for (int i = 0; i < 4; i++)
            GLOAD16(gA[i], AsB + i * 4096 + wave * 1024);
        #pragma unroll
        for (int i = 0; i < 4; i++)
            GLOAD16(gB[i], BsB + i * 4096 + wave * 1024);
        #pragma unroll
        for (int i = 0; i < 4; i++) { gA[i] += 64; gB[i] += 64; }
        __syncthreads();
        #pragma unroll
        for (int kk = 0; kk < 2; kk++) {
            int off = kk ? off1 : off0;
            bf16x8 a[4], b[4];
            #pragma unroll
            for (int m = 0; m < 4; m++) a[m] = *(const bf16x8*)(Abase + m * 2048 + off);
            #pragma unroll
            for (int n = 0; n < 4; n++) b[n] = *(const bf16x8*)(Bbase + n * 2048 + off);
            #pragma unroll
            for (int m = 0; m < 4; m++)
                #pragma unroll
                for (int n = 0; n < 4; n++)
                    acc[m][n] = __builtin_amdgcn_mfma_f32_16x16x32_bf16(a[m], b[n], acc[m][n], 0, 0, 0);
        }
        __syncthreads();
    }

    // epilogue: bias + sigmoid-form gelu (abs err ~1e-3 << bf16 quantum)
    const float* b1e = b1 + e * FD + n0;
    #pragma unroll
    for (int n = 0; n < 4; n++) {
        int col = wc * 64 + n * 16 + laneR;
        float bias = b1e[col];
        #pragma unroll
        for (int m = 0; m < 4; m++) {
            int rbase = wr * 64 + m * 16 + (lane >> 4) * 4;
            #pragma unroll
            for (int r = 0; r < 4; r++) {
                float v = acc[m][n][r] + bias;
                float u = v + 0.044715f * v * v * v;
                float g = v / (1.0f + __expf(-1.5957692f * u));
                Hact[(size_t)(row0 + rbase + r) * FD + n0 + col] = f2bf(g);
            }
        }
    }
}

// ---------------- grouped GEMM 2: Out2[cslot] = H_act @ w2 + b2 (bf16, compacted) ----------------

__global__ __launch_bounds__(256, 2) void gemm2_kernel(
    const u16* __restrict__ Hact, const u16* __restrict__ W2t,
    const float* __restrict__ b2, const int* __restrict__ sorted_rid,
    const int* __restrict__ padcum,
    const int* __restrict__ tileE, const int* __restrict__ tileRow,
    const int* __restrict__ numTiles, u16* __restrict__ Out2)
{
    int bid = blockIdx.x;
    int xcd = bid & 7, slot = bid >> 3;
    int mt = xcd + (slot / NTN2) * 8;
    int n0 = (slot % NTN2) * 128;
    if (mt >= *numTiles) return;
    int e = tileE[mt];
    int row0 = tileRow[mt];

    __shared__ __align__(16) u16 As[128 * 64];
    __shared__ __align__(16) u16 Bs[128 * 64];

    int tid = threadIdx.x;
    int wave = tid >> 6, lane = tid & 63;
    int laneR = lane & 15;

    const u16* gA[4]; const u16* gB[4];
    #pragma unroll
    for (int i = 0; i < 4; i++) {
        int c = i * 256 + tid;
        int r = c >> 3, kc = c & 7;
        int kcs = kc ^ (r & 7);
        gA[i] = Hact + (size_t)(row0 + r) * FD + kcs * 8;
        gB[i] = W2t + ((size_t)e * HD + (n0 + r)) * FD + kcs * 8;
    }
    char* AsB = (char*)As; char* BsB = (char*)Bs;

    f32x4 acc[4][4] = {};

    int wr = wave >> 1, wc = wave & 1;
    int off0 = (((lane >> 4) ^ (lane & 7)) << 4);
    int off1 = off0 ^ 64;
    const char* Abase = AsB + (wr * 64 + laneR) * 128;
    const char* Bbase = BsB + (wc * 64 + laneR) * 128;

    for (int kt = 0; kt < FD / 64; kt++) {
        #pragma unroll
        for (int i = 0; i < 4; i++)
            GLOAD16(gA[i], AsB + i * 4096 + wave * 1024);
        #pragma unroll
        for (int i = 0; i < 4; i++)
            GLOAD16(gB[i], BsB + i * 4096 + wave * 1024);
        #pragma unroll
        for (int i = 0; i < 4; i++) { gA[i] += 64; gB[i] += 64; }
        __syncthreads();
        #pragma unroll
        for (int kk = 0; kk < 2; kk++) {
            int off = kk ? off1 : off0;
            bf16x8 a[4], b[4];
            #pragma unroll
            for (int m = 0; m < 4; m++) a[m] = *(const bf16x8*)(Abase + m * 2048 + off);
            #pragma unroll
            for (int n = 0; n < 4; n++) b[n] = *(const bf16x8*)(Bbase + n * 2048 + off);
            #pragma unroll
            for (int m = 0; m < 4; m++)
                #pragma unroll
                for (int n = 0; n < 4; n++)
                    acc[m][n] = __builtin_amdgcn_mfma_f32_16x16x32_bf16(a[m], b[n], acc[m][n], 0, 0, 0);
        }
        __syncthreads();
    }

    // epilogue: bias -> bf16 store into COMPACTED slot-major Out2 (skip pad rows)
    const float* b2e = b2 + e * HD + n0;
    int pc = padcum[e];
    #pragma unroll
    for (int m = 0; m < 4; m++) {
        int rbase = wr * 64 + m * 16 + (lane >> 4) * 4;
        #pragma unroll
        for (int r = 0; r < 4; r++) {
            int rr = row0 + rbase + r;
            int rid = sorted_rid[rr];
            if (rid < 0) continue;               // padding row: no storage
            u16* orow = Out2 + (size_t)(rr - pc) * HD + n0;
            #pragma unroll
            for (int n = 0; n < 4; n++) {
                int col = wc * 64 + n * 16 + laneR;
                orow[col] = f2bf(acc[m][n][r] + b2e[col]);
            }
        }
    }
}

// ---------------- combine: y[t] = w0*Out2[inv[2t]] + w1*Out2[inv[2t+1]] ----------------

__global__ void combine_kernel(const u16* __restrict__ Out2, const int* __restrict__ inv,
                               const float* __restrict__ ew, float* __restrict__ y) {
    int i = blockIdx.x * blockDim.x + threadIdx.x;   // one thread = 8 cols of one token
    int tok = i >> 7;
    int c0 = (i & 127) << 3;
    int s0 = inv[2 * tok], s1 = inv[2 * tok + 1];
    float w0 = ew[2 * tok], w1 = ew[2 * tok + 1];
    union { uint4 v; u16 s[8]; } a, b;
    a.v = *(const uint4*)(Out2 + (size_t)s0 * HD + c0);
    b.v = *(const uint4*)(Out2 + (size_t)s1 * HD + c0);
    float out[8];
    #pragma unroll
    for (int j = 0; j < 8; j++) {
        union { u32 u; float f; } fa, fb;
        fa.u = (u32)a.s[j] << 16;
        fb.u = (u32)b.s[j] << 16;
        out[j] = w0 * fa.f + w1 * fb.f;
    }
    float4* yp = (float4*)(y + (size_t)tok * HD + c0);
    yp[0] = *(const float4*)&out[0];
    yp[1] = *(const float4*)&out[4];
}

// ---------------- launch ----------------

extern "C" void kernel_launch(void* const* d_in, const int* in_sizes, int n_in,
                              void* d_out, int out_size, void* d_ws, size_t ws_size,
                              hipStream_t stream) {
    const float* x  = (const float*)d_in[0];
    const float* ew = (const float*)d_in[1];
    const int*   te = (const int*)d_in[2];
    const float* w1 = (const float*)d_in[3];
    const float* b1 = (const float*)d_in[4];
    const float* w2 = (const float*)d_in[5];
    const float* b2 = (const float*)d_in[6];
    float* y = (float*)d_out;

    char* ws = (char*)d_ws;
    // Xb[0,32M) W1t[32M,64M) W2t[64M,96M) Hact[96M,228M) ip[228M+]
    // Out2 (compacted, 32768 x 1024 bf16 = 64MB) overlays Xb+W1t exactly
    // (both dead once gemm1 finishes; W2t untouched).
    u16* Xb   = (u16*)(ws);                      // 33,554,432 B
    u16* W1t  = (u16*)(ws + 33554432);           // 33,554,432 B
    u16* Out2 = (u16*)(ws);                      // 67,108,864 B (overlay)
    u16* W2t  = (u16*)(ws + 67108864);           // 33,554,432 B
    u16* Hact = (u16*)(ws + 100663296);          // 138,412,032 B (RP_MAX x 2048 bf16)
    char* ip  = ws + 239075328;
    int* numTiles = (int*)(ip);
    int* padcum   = (int*)(ip + 64);
    int* tileE    = (int*)(ip + 128);            // 1056 B
    int* tileRow  = (int*)(ip + 2048);           // 1056 B
    int* sorted   = (int*)(ip + 4096);           // 135,168 B
    int* inv      = (int*)(ip + 139264);         // 131,072 B

    // fused prep: convert_x | w1^T | w2^T | routing (last block)
    mega_prep<<<NB_PREP, 1024, 0, stream>>>(
        x, Xb, w1, W1t, w2, W2t, te, sorted, inv, tileE, tileRow, numTiles, padcum);

    // grouped GEMM 1
    gemm1_kernel<<<MAX_MT * NTN1, 256, 0, stream>>>(
        Xb, W1t, b1, sorted, tileE, tileRow, numTiles, Hact);

    // grouped GEMM 2 (compacted plain stores)
    gemm2_kernel<<<MAX_MT * NTN2, 256, 0, stream>>>(
        Hact, W2t, b2, sorted, padcum, tileE, tileRow, numTiles, Out2);

    // weighted topk combine
    combine_kernel<<<(TOKENS * 128) / 256, 256, 0, stream>>>(Out2, inv, ew, y);
}

// Round 8
// 452.213 us; speedup vs baseline: 1.5792x; 1.0803x over previous
//
#include <hip/hip_runtime.h>
#include <hip/hip_bf16.h>
#include <math.h>

// Problem constants (B=4, S=4096 -> T=16384 tokens)
#define TOKENS 16384
#define HD 1024
#define FD 2048
#define NEXP 8
#define RP_MAX (264 * 128)   // max padded routed rows
#define MAX_MT 264           // max 128-row m-tiles (divisible by 8 for XCD swizzle)
#define NTN1 16              // gemm1 n-tiles: FD/128
#define NTN2 8               // gemm2 n-tiles: HD/128

// mega-prep block ranges (1024 threads/block)
#define NB_CONV 2048         // convert_x
#define NB_W1   1024         // w1 transpose: 8 experts x 8 k-tiles x 16 n-tiles (128x128)
#define NB_W2   1024         // w2 transpose: 8 experts x 16 k-tiles x 8 n-tiles
#define NB_PREP (NB_CONV + NB_W1 + NB_W2 + 1)   // +1 routing block

typedef __bf16 bf16x8 __attribute__((ext_vector_type(8)));
typedef float f32x4 __attribute__((ext_vector_type(4)));
typedef unsigned short u16;
typedef unsigned int u32;
typedef unsigned long long u64;

__device__ __forceinline__ u16 f2bf(float f) {
    union { float f; u32 u; } v; v.f = f;
    return (u16)((v.u + 0x7FFFu + ((v.u >> 16) & 1u)) >> 16);
}

#define GLOAD16(g, l) __builtin_amdgcn_global_load_lds( \
    (const __attribute__((address_space(1))) u32*)(g),  \
    (__attribute__((address_space(3))) u32*)(l), 16, 0, 0)

// ==================================================================
// mega-prep: convert_x | w1 transpose | w2 transpose | routing
// transpose: 128x128 tile/block, XOR-swizzled LDS (slot = (n>>2)^(k&31)),
// float4 loads (16B/lane) -> bf16 -> ds_write_b64 -> uint4 stores (16B/lane).
// ==================================================================
__global__ __launch_bounds__(1024) void mega_prep(
    const float* __restrict__ x, u16* __restrict__ xb,
    const float* __restrict__ w1, u16* __restrict__ w1t,
    const float* __restrict__ w2, u16* __restrict__ w2t,
    const int* __restrict__ te,
    int* sorted_rid, int* inv, int* tileE, int* tileRow,
    int* numTiles, int* padcum)
{
    __shared__ __align__(16) char ldsT[32768];          // 128 rows x 32 slots x 8B
    __shared__ int cntS[NEXP], offsS[NEXP], fillS[NEXP], padS[NEXP], ntS;
    int b = blockIdx.x;
    int tid = threadIdx.x;

    if (b < NB_CONV) {                       // ---- convert x -> bf16
        int i = b * 1024 + tid;              // one thread = 8 elems
        const float4* xv = (const float4*)x;
        float4 a = xv[i * 2], c = xv[i * 2 + 1];
        union { u16 s[8]; uint4 v; } o;
        o.s[0] = f2bf(a.x); o.s[1] = f2bf(a.y); o.s[2] = f2bf(a.z); o.s[3] = f2bf(a.w);
        o.s[4] = f2bf(c.x); o.s[5] = f2bf(c.y); o.s[6] = f2bf(c.z); o.s[7] = f2bf(c.w);
        *(uint4*)(xb + (size_t)i * 8) = o.v;
        return;
    }
    if (b < NB_CONV + NB_W1 + NB_W2) {       // ---- weight transpose [E][K][N]->[E][N][K]
        const float* src; u16* dst; int K, N, n0, k0, e;
        if (b < NB_CONV + NB_W1) {
            int bb = b - NB_CONV;
            e = bb >> 7; int r = bb & 127;   // 8 k-tiles x 16 n-tiles
            n0 = (r & 15) * 128; k0 = (r >> 4) * 128;
            K = HD; N = FD; src = w1; dst = w1t;
        } else {
            int bb = b - NB_CONV - NB_W1;
            e = bb >> 7; int r = bb & 127;   // 16 k-tiles x 8 n-tiles
            n0 = (r & 7) * 128; k0 = (r >> 3) * 128;
            K = FD; N = HD; src = w2; dst = w2t;
        }
        const float* s = src + (size_t)e * K * N + (size_t)k0 * N + n0;
        u16* d = dst + (size_t)e * N * K + (size_t)n0 * K + k0;
        // load phase: 32 tx (4 cols each) x 32 ty, 4 k-passes; 16 elems/thread
        int tx = tid & 31, ty = tid >> 5;
        #pragma unroll
        for (int p = 0; p < 4; p++) {
            int k = p * 32 + ty;
            float4 v = *(const float4*)(s + (size_t)k * N + tx * 4);
            union { u16 q[4]; u64 u; } o;
            o.q[0] = f2bf(v.x); o.q[1] = f2bf(v.y); o.q[2] = f2bf(v.z); o.q[3] = f2bf(v.w);
            int phys = tx ^ (k & 31);
            *(u64*)(ldsT + k * 256 + phys * 8) = o.u;
        }
        __syncthreads();
        // store phase: 16 tx2 (8 k's each) x 64 ty2 (n), 2 n-passes
        int tx2 = tid & 15, ty2 = tid >> 4;
        #pragma unroll
        for (int p = 0; p < 2; p++) {
            int n = p * 64 + ty2;
            union { u16 q[8]; uint4 u; } o;
            #pragma unroll
            for (int j = 0; j < 8; j++) {
                int k = tx2 * 8 + j;
                int phys = (n >> 2) ^ (k & 31);
                o.q[j] = *(const u16*)(ldsT + k * 256 + phys * 8 + (n & 3) * 2);
            }
            *(uint4*)(d + (size_t)n * K + tx2 * 8) = o.u;
        }
        return;
    }

    // ---- routing (single block, 1024 threads = 16 waves)
    int lane = tid & 63;
    if (tid < NEXP) cntS[tid] = 0;
    __syncthreads();
    int h[NEXP] = {0, 0, 0, 0, 0, 0, 0, 0};
    for (int j = tid; j < TOKENS * 2; j += 1024) {
        int v = te[j];
        #pragma unroll
        for (int e = 0; e < NEXP; e++) h[e] += (v == e);
    }
    #pragma unroll
    for (int e = 0; e < NEXP; e++) {
        int s = h[e];
        #pragma unroll
        for (int o = 32; o > 0; o >>= 1) s += __shfl_down(s, o, 64);
        if (lane == 0 && s) atomicAdd(&cntS[e], s);
    }
    __syncthreads();
    if (tid == 0) {
        int o = 0, t = 0, pc = 0;
        for (int e = 0; e < NEXP; e++) {
            offsS[e] = o; fillS[e] = 0;
            int pad = o - pc;
            padS[e] = pad; padcum[e] = pad;
            int c = cntS[e];
            int nt = (c + 127) >> 7;
            for (int i = 0; i < nt; i++) { tileE[t] = e; tileRow[t] = o + i * 128; t++; }
            o += nt * 128; pc += c;
        }
        ntS = t;
        *numTiles = t;
    }
    __syncthreads();
    int tot = ntS * 128;
    for (int i = tid; i < tot; i += 1024) sorted_rid[i] = -1;
    __syncthreads();
    for (int j = tid; j < TOKENS * 2; j += 1024) {   // full waves always
        int v = te[j];
        int base = 0;
        #pragma unroll
        for (int e = 0; e < NEXP; e++) {
            unsigned long long m = __ballot(v == e);
            if (m) {
                int ldr = (int)__builtin_ctzll(m);
                int bb = 0;
                if (lane == ldr) bb = atomicAdd(&fillS[e], __popcll(m));
                bb = __shfl(bb, ldr, 64);
                if (v == e) base = bb + (int)__popcll(m & ((1ull << lane) - 1ull));
            }
        }
        int p = offsS[v] + base;
        sorted_rid[p] = j;
        inv[j] = p - padS[v];            // compacted (pad-free) slot
    }
}

// ==================================================================
// 128x128 grouped-GEMM core (round-5 proven, ~745 TF): BK=64, 4 waves,
// single LDS buffer, stage -> sync -> 32 MFMA -> sync. T2 XOR swizzle
// via pre-swizzled global source (0 conflicts). T1 XCD-bijective grid.
// ==================================================================

// ---------------- grouped GEMM 1: H_act = gelu(X[gather] @ w1 + b1) ----------------

__global__ __launch_bounds__(256, 2) void gemm1_kernel(
    const u16* __restrict__ Xb, const u16* __restrict__ W1t,
    const float* __restrict__ b1, const int* __restrict__ sorted_rid,
    const int* __restrict__ tileE, const int* __restrict__ tileRow,
    const int* __restrict__ numTiles, u16* __restrict__ Hact)
{
    int bid = blockIdx.x;
    int xcd = bid & 7, slot = bid >> 3;
    int mt = xcd + (slot / NTN1) * 8;
    int n0 = (slot % NTN1) * 128;
    if (mt >= *numTiles) return;
    int e = tileE[mt];
    int row0 = tileRow[mt];

    __shared__ __align__(16) u16 As[128 * 64];
    __shared__ __align__(16) u16 Bs[128 * 64];

    int tid = threadIdx.x;
    int wave = tid >> 6, lane = tid & 63;
    int laneR = lane & 15;

    const u16* gA[4]; const u16* gB[4];
    #pragma unroll
    for (int i = 0; i < 4; i++) {
        int c = i * 256 + tid;
        int r = c >> 3, kc = c & 7;
        int kcs = kc ^ (r & 7);
        int rid = sorted_rid[row0 + r];
        int tok = rid < 0 ? 0 : (rid >> 1);
        gA[i] = Xb + (size_t)tok * HD + kcs * 8;
        gB[i] = W1t + ((size_t)e * FD + (n0 + r)) * HD + kcs * 8;
    }
    char* AsB = (char*)As; char* BsB = (char*)Bs;

    f32x4 acc[4][4] = {};

    int wr = wave >> 1, wc = wave & 1;
    int off0 = (((lane >> 4) ^ (lane & 7)) << 4);
    int off1 = off0 ^ 64;
    const char* Abase = AsB + (wr * 64 + laneR) * 128;
    const char* Bbase = BsB + (wc * 64 + laneR) * 128;

    for (int kt = 0; kt < HD / 64; kt++) {
        #pragma unroll
        for (int i = 0; i < 4; i++)
            GLOAD16(gA[i], AsB + i * 4096 + wave * 1024);
        #pragma unroll
        for (int i = 0; i < 4; i++)
            GLOAD16(gB[i], BsB + i * 4096 + wave * 1024);
        #pragma unroll
        for (int i = 0; i < 4; i++) { gA[i] += 64; gB[i] += 64; }
        __syncthreads();
        #pragma unroll
        for (int kk = 0; kk < 2; kk++) {
            int off = kk ? off1 : off0;
            bf16x8 a[4], b[4];
            #pragma unroll
            for (int m = 0; m < 4; m++) a[m] = *(const bf16x8*)(Abase + m * 2048 + off);
            #pragma unroll
            for (int n = 0; n < 4; n++) b[n] = *(const bf16x8*)(Bbase + n * 2048 + off);
            #pragma unroll
            for (int m = 0; m < 4; m++)
                #pragma unroll
                for (int n = 0; n < 4; n++)
                    acc[m][n] = __builtin_amdgcn_mfma_f32_16x16x32_bf16(a[m], b[n], acc[m][n], 0, 0, 0);
        }
        __syncthreads();
    }

    // epilogue: bias + sigmoid-form gelu (abs err ~1e-3 << bf16 quantum)
    const float* b1e = b1 + e * FD + n0;
    #pragma unroll
    for (int n = 0; n < 4; n++) {
        int col = wc * 64 + n * 16 + laneR;
        float bias = b1e[col];
        #pragma unroll
        for (int m = 0; m < 4; m++) {
            int rbase = wr * 64 + m * 16 + (lane >> 4) * 4;
            #pragma unroll
            for (int r = 0; r < 4; r++) {
                float v = acc[m][n][r] + bias;
                float u = v + 0.044715f * v * v * v;
                float g = v / (1.0f + __expf(-1.5957692f * u));
                Hact[(size_t)(row0 + rbase + r) * FD + n0 + col] = f2bf(g);
            }
        }
    }
}

// ---------------- grouped GEMM 2: Out2[cslot] = H_act @ w2 + b2 (bf16, compacted) ----------------

__global__ __launch_bounds__(256, 2) void gemm2_kernel(
    const u16* __restrict__ Hact, const u16* __restrict__ W2t,
    const float* __restrict__ b2, const int* __restrict__ sorted_rid,
    const int* __restrict__ padcum,
    const int* __restrict__ tileE, const int* __restrict__ tileRow,
    const int* __restrict__ numTiles, u16* __restrict__ Out2)
{
    int bid = blockIdx.x;
    int xcd = bid & 7, slot = bid >> 3;
    int mt = xcd + (slot / NTN2) * 8;
    int n0 = (slot % NTN2) * 128;
    if (mt >= *numTiles) return;
    int e = tileE[mt];
    int row0 = tileRow[mt];

    __shared__ __align__(16) u16 As[128 * 64];
    __shared__ __align__(16) u16 Bs[128 * 64];

    int tid = threadIdx.x;
    int wave = tid >> 6, lane = tid & 63;
    int laneR = lane & 15;

    const u16* gA[4]; const u16* gB[4];
    #pragma unroll
    for (int i = 0; i < 4; i++) {
        int c = i * 256 + tid;
        int r = c >> 3, kc = c & 7;
        int kcs = kc ^ (r & 7);
        gA[i] = Hact + (size_t)(row0 + r) * FD + kcs * 8;
        gB[i] = W2t + ((size_t)e * HD + (n0 + r)) * FD + kcs * 8;
    }
    char* AsB = (char*)As; char* BsB = (char*)Bs;

    f32x4 acc[4][4] = {};

    int wr = wave >> 1, wc = wave & 1;
    int off0 = (((lane >> 4) ^ (lane & 7)) << 4);
    int off1 = off0 ^ 64;
    const char* Abase = AsB + (wr * 64 + laneR) * 128;
    const char* Bbase = BsB + (wc * 64 + laneR) * 128;

    for (int kt = 0; kt < FD / 64; kt++) {
        #pragma unroll
        for (int i = 0; i < 4; i++)
            GLOAD16(gA[i], AsB + i * 4096 + wave * 1024);
        #pragma unroll
        for (int i = 0; i < 4; i++)
            GLOAD16(gB[i], BsB + i * 4096 + wave * 1024);
        #pragma unroll
        for (int i = 0; i < 4; i++) { gA[i] += 64; gB[i] += 64; }
        __syncthreads();
        #pragma unroll
        for (int kk = 0; kk < 2; kk++) {
            int off = kk ? off1 : off0;
            bf16x8 a[4], b[4];
            #pragma unroll
            for (int m = 0; m < 4; m++) a[m] = *(const bf16x8*)(Abase + m * 2048 + off);
            #pragma unroll
            for (int n = 0; n < 4; n++) b[n] = *(const bf16x8*)(Bbase + n * 2048 + off);
            #pragma unroll
            for (int m = 0; m < 4; m++)
                #pragma unroll
                for (int n = 0; n < 4; n++)
                    acc[m][n] = __builtin_amdgcn_mfma_f32_16x16x32_bf16(a[m], b[n], acc[m][n], 0, 0, 0);
        }
        __syncthreads();
    }

    // epilogue: bias -> bf16 store into COMPACTED slot-major Out2 (skip pad rows)
    const float* b2e = b2 + e * HD + n0;
    int pc = padcum[e];
    #pragma unroll
    for (int m = 0; m < 4; m++) {
        int rbase = wr * 64 + m * 16 + (lane >> 4) * 4;
        #pragma unroll
        for (int r = 0; r < 4; r++) {
            int rr = row0 + rbase + r;
            int rid = sorted_rid[rr];
            if (rid < 0) continue;               // padding row: no storage
            u16* orow = Out2 + (size_t)(rr - pc) * HD + n0;
            #pragma unroll
            for (int n = 0; n < 4; n++) {
                int col = wc * 64 + n * 16 + laneR;
                orow[col] = f2bf(acc[m][n][r] + b2e[col]);
            }
        }
    }
}

// ---------------- combine: y[t] = w0*Out2[inv[2t]] + w1*Out2[inv[2t+1]] ----------------

__global__ void combine_kernel(const u16* __restrict__ Out2, const int* __restrict__ inv,
                               const float* __restrict__ ew, float* __restrict__ y) {
    int i = blockIdx.x * blockDim.x + threadIdx.x;   // one thread = 8 cols of one token
    int tok = i >> 7;
    int c0 = (i & 127) << 3;
    int s0 = inv[2 * tok], s1 = inv[2 * tok + 1];
    float w0 = ew[2 * tok], w1 = ew[2 * tok + 1];
    union { uint4 v; u16 s[8]; } a, b;
    a.v = *(const uint4*)(Out2 + (size_t)s0 * HD + c0);
    b.v = *(const uint4*)(Out2 + (size_t)s1 * HD + c0);
    float out[8];
    #pragma unroll
    for (int j = 0; j < 8; j++) {
        union { u32 u; float f; } fa, fb;
        fa.u = (u32)a.s[j] << 16;
        fb.u = (u32)b.s[j] << 16;
        out[j] = w0 * fa.f + w1 * fb.f;
    }
    float4* yp = (float4*)(y + (size_t)tok * HD + c0);
    yp[0] = *(const float4*)&out[0];
    yp[1] = *(const float4*)&out[4];
}

// ---------------- launch ----------------

extern "C" void kernel_launch(void* const* d_in, const int* in_sizes, int n_in,
                              void* d_out, int out_size, void* d_ws, size_t ws_size,
                              hipStream_t stream) {
    const float* x  = (const float*)d_in[0];
    const float* ew = (const float*)d_in[1];
    const int*   te = (const int*)d_in[2];
    const float* w1 = (const float*)d_in[3];
    const float* b1 = (const float*)d_in[4];
    const float* w2 = (const float*)d_in[5];
    const float* b2 = (const float*)d_in[6];
    float* y = (float*)d_out;

    char* ws = (char*)d_ws;
    // Xb[0,32M) W1t[32M,64M) W2t[64M,96M) Hact[96M,228M) ip[228M+]
    // Out2 (compacted, 32768 x 1024 bf16 = 64MB) overlays Xb+W1t.
    u16* Xb   = (u16*)(ws);                      // 33,554,432 B
    u16* W1t  = (u16*)(ws + 33554432);           // 33,554,432 B
    u16* Out2 = (u16*)(ws);                      // 67,108,864 B (overlay)
    u16* W2t  = (u16*)(ws + 67108864);           // 33,554,432 B
    u16* Hact = (u16*)(ws + 100663296);          // 138,412,032 B (RP_MAX x 2048 bf16)
    char* ip  = ws + 239075328;
    int* numTiles = (int*)(ip);
    int* padcum   = (int*)(ip + 64);
    int* tileE    = (int*)(ip + 128);            // 1056 B
    int* tileRow  = (int*)(ip + 2048);           // 1056 B
    int* sorted   = (int*)(ip + 4096);           // 135,168 B
    int* inv      = (int*)(ip + 139264);         // 131,072 B

    // fused prep: convert_x | w1^T | w2^T | routing (last block)
    mega_prep<<<NB_PREP, 1024, 0, stream>>>(
        x, Xb, w1, W1t, w2, W2t, te, sorted, inv, tileE, tileRow, numTiles, padcum);

    // grouped GEMM 1
    gemm1_kernel<<<MAX_MT * NTN1, 256, 0, stream>>>(
        Xb, W1t, b1, sorted, tileE, tileRow, numTiles, Hact);

    // grouped GEMM 2 (compacted plain stores)
    gemm2_kernel<<<MAX_MT * NTN2, 256, 0, stream>>>(
        Hact, W2t, b2, sorted, padcum, tileE, tileRow, numTiles, Out2);

    // weighted topk combine
    combine_kernel<<<(TOKENS * 128) / 256, 256, 0, stream>>>(Out2, inv, ew, y);
}

// Round 11
// 445.454 us; speedup vs baseline: 1.6032x; 1.0152x over previous
//
#include <hip/hip_runtime.h>
#include <hip/hip_bf16.h>
#include <math.h>

// Problem constants (B=4, S=4096 -> T=16384 tokens)
#define TOKENS 16384
#define HD 1024
#define FD 2048
#define NEXP 8
#define RP_MAX (264 * 128)   // max padded routed rows
#define MAX_MT 264           // max 128-row m-tiles (divisible by 8 for XCD swizzle)
#define NTN1 16              // gemm1 n-tiles: FD/128
#define NTN2 8               // gemm2 n-tiles: HD/128

// mega-prep block ranges (1024 threads/block)
#define NB_CONV 2048         // convert_x
#define NB_W1   1024         // w1 transpose: 8 experts x 8 k-tiles x 16 n-tiles (128x128)
#define NB_W2   1024         // w2 transpose: 8 experts x 16 k-tiles x 8 n-tiles
#define NB_PREP (NB_CONV + NB_W1 + NB_W2 + 1)   // +1 routing block

typedef __bf16 bf16x8 __attribute__((ext_vector_type(8)));
typedef float f32x4 __attribute__((ext_vector_type(4)));
typedef unsigned short u16;
typedef unsigned int u32;
typedef unsigned long long u64;

__device__ __forceinline__ u16 f2bf(float f) {
    union { float f; u32 u; } v; v.f = f;
    return (u16)((v.u + 0x7FFFu + ((v.u >> 16) & 1u)) >> 16);
}

// pack two f32 -> two bf16 in one instruction (lo = src0, hi = src1)
__device__ __forceinline__ u32 pk_bf16(float lo, float hi) {
    u32 p;
    asm("v_cvt_pk_bf16_f32 %0, %1, %2" : "=v"(p) : "v"(lo), "v"(hi));
    return p;
}

// gelu tanh/sigmoid form: v * sigmoid(1.5957692*(v + 0.044715 v^3))
__device__ __forceinline__ float gelu_f(float v) {
    float u = __builtin_fmaf(0.044715f * v * v, v, v);   // v + 0.044715 v^3 (FIXED)
    float ez = __builtin_amdgcn_exp2f(-2.302208f * u);   // exp(-1.5957692 u)
    return v * __builtin_amdgcn_rcpf(1.0f + ez);
}

#define GLOAD16(g, l) __builtin_amdgcn_global_load_lds( \
    (const __attribute__((address_space(1))) u32*)(g),  \
    (__attribute__((address_space(3))) u32*)(l), 16, 0, 0)

// ==================================================================
// mega-prep: convert_x | w1 transpose | w2 transpose | routing
// ==================================================================
__global__ __launch_bounds__(1024) void mega_prep(
    const float* __restrict__ x, u16* __restrict__ xb,
    const float* __restrict__ w1, u16* __restrict__ w1t,
    const float* __restrict__ w2, u16* __restrict__ w2t,
    const int* __restrict__ te,
    int* sorted_rid, int* inv, int* tileE, int* tileRow,
    int* numTiles, int* padcum)
{
    __shared__ __align__(16) char ldsT[32768];          // 128 rows x 32 slots x 8B
    __shared__ int cntS[NEXP], offsS[NEXP], fillS[NEXP], padS[NEXP], ntS;
    int b = blockIdx.x;
    int tid = threadIdx.x;

    if (b < NB_CONV) {                       // ---- convert x -> bf16
        int i = b * 1024 + tid;              // one thread = 8 elems
        const float4* xv = (const float4*)x;
        float4 a = xv[i * 2], c = xv[i * 2 + 1];
        union { u16 s[8]; uint4 v; } o;
        o.s[0] = f2bf(a.x); o.s[1] = f2bf(a.y); o.s[2] = f2bf(a.z); o.s[3] = f2bf(a.w);
        o.s[4] = f2bf(c.x); o.s[5] = f2bf(c.y); o.s[6] = f2bf(c.z); o.s[7] = f2bf(c.w);
        *(uint4*)(xb + (size_t)i * 8) = o.v;
        return;
    }
    if (b < NB_CONV + NB_W1 + NB_W2) {       // ---- weight transpose [E][K][N]->[E][N][K]
        const float* src; u16* dst; int K, N, n0, k0, e;
        if (b < NB_CONV + NB_W1) {
            int bb = b - NB_CONV;
            e = bb >> 7; int r = bb & 127;   // 8 k-tiles x 16 n-tiles
            n0 = (r & 15) * 128; k0 = (r >> 4) * 128;
            K = HD; N = FD; src = w1; dst = w1t;
        } else {
            int bb = b - NB_CONV - NB_W1;
            e = bb >> 7; int r = bb & 127;   // 16 k-tiles x 8 n-tiles
            n0 = (r & 7) * 128; k0 = (r >> 3) * 128;
            K = FD; N = HD; src = w2; dst = w2t;
        }
        const float* s = src + (size_t)e * K * N + (size_t)k0 * N + n0;
        u16* d = dst + (size_t)e * N * K + (size_t)n0 * K + k0;
        int tx = tid & 31, ty = tid >> 5;
        #pragma unroll
        for (int p = 0; p < 4; p++) {
            int k = p * 32 + ty;
            float4 v = *(const float4*)(s + (size_t)k * N + tx * 4);
            union { u16 q[4]; u64 u; } o;
            o.q[0] = f2bf(v.x); o.q[1] = f2bf(v.y); o.q[2] = f2bf(v.z); o.q[3] = f2bf(v.w);
            int phys = tx ^ (k & 31);
            *(u64*)(ldsT + k * 256 + phys * 8) = o.u;
        }
        __syncthreads();
        int tx2 = tid & 15, ty2 = tid >> 4;
        #pragma unroll
        for (int p = 0; p < 2; p++) {
            int n = p * 64 + ty2;
            union { u16 q[8]; uint4 u; } o;
            #pragma unroll
            for (int j = 0; j < 8; j++) {
                int k = tx2 * 8 + j;
                int phys = (n >> 2) ^ (k & 31);
                o.q[j] = *(const u16*)(ldsT + k * 256 + phys * 8 + (n & 3) * 2);
            }
            *(uint4*)(d + (size_t)n * K + tx2 * 8) = o.u;
        }
        return;
    }

    // ---- routing (single block, 1024 threads = 16 waves)
    int lane = tid & 63;
    if (tid < NEXP) cntS[tid] = 0;
    __syncthreads();
    int h[NEXP] = {0, 0, 0, 0, 0, 0, 0, 0};
    for (int j = tid; j < TOKENS * 2; j += 1024) {
        int v = te[j];
        #pragma unroll
        for (int e = 0; e < NEXP; e++) h[e] += (v == e);
    }
    #pragma unroll
    for (int e = 0; e < NEXP; e++) {
        int s = h[e];
        #pragma unroll
        for (int o = 32; o > 0; o >>= 1) s += __shfl_down(s, o, 64);
        if (lane == 0 && s) atomicAdd(&cntS[e], s);
    }
    __syncthreads();
    if (tid == 0) {
        int o = 0, t = 0, pc = 0;
        for (int e = 0; e < NEXP; e++) {
            offsS[e] = o; fillS[e] = 0;
            int pad = o - pc;
            padS[e] = pad; padcum[e] = pad;
            int c = cntS[e];
            int nt = (c + 127) >> 7;
            for (int i = 0; i < nt; i++) { tileE[t] = e; tileRow[t] = o + i * 128; t++; }
            o += nt * 128; pc += c;
        }
        ntS = t;
        *numTiles = t;
    }
    __syncthreads();
    int tot = ntS * 128;
    for (int i = tid; i < tot; i += 1024) sorted_rid[i] = -1;
    __syncthreads();
    for (int j = tid; j < TOKENS * 2; j += 1024) {   // full waves always
        int v = te[j];
        int base = 0;
        #pragma unroll
        for (int e = 0; e < NEXP; e++) {
            unsigned long long m = __ballot(v == e);
            if (m) {
                int ldr = (int)__builtin_ctzll(m);
                int bb = 0;
                if (lane == ldr) bb = atomicAdd(&fillS[e], __popcll(m));
                bb = __shfl(bb, ldr, 64);
                if (v == e) base = bb + (int)__popcll(m & ((1ull << lane) - 1ull));
            }
        }
        int p = offsS[v] + base;
        sorted_rid[p] = j;
        inv[j] = p - padS[v];            // compacted (pad-free) slot
    }
}

// ==================================================================
// 128x128 grouped-GEMM core (proven ~800 TF): BK=64, 4 waves, single
// LDS buffer, stage -> sync -> 32 MFMA -> sync. T2 XOR swizzle via
// pre-swizzled global source (0 conflicts). T1 XCD-bijective grid.
// SWAPPED-OPERAND MFMA (proven bit-exact by round-9/10 forensics):
// acc[m][n] = mfma(b[n], a[m], acc) -> lane holds 4 column-consecutive
// outputs: row-offset = laneR, col-offset = kgrp*4 + reg.
// ==================================================================

// ---------------- grouped GEMM 1: H_act = gelu(X[gather] @ w1 + b1) ----------------

__global__ __launch_bounds__(256, 2) void gemm1_kernel(
    const u16* __restrict__ Xb, const u16* __restrict__ W1t,
    const float* __restrict__ b1, const int* __restrict__ sorted_rid,
    const int* __restrict__ tileE, const int* __restrict__ tileRow,
    const int* __restrict__ numTiles, u16* __restrict__ Hact)
{
    int bid = blockIdx.x;
    int xcd = bid & 7, slot = bid >> 3;
    int mt = xcd + (slot / NTN1) * 8;
    int n0 = (slot % NTN1) * 128;
    if (mt >= *numTiles) return;
    int e = tileE[mt];
    int row0 = tileRow[mt];

    __shared__ __align__(16) u16 As[128 * 64];
    __shared__ __align__(16) u16 Bs[128 * 64];

    int tid = threadIdx.x;
    int wave = tid >> 6, lane = tid & 63;
    int laneR = lane & 15, kgrp = lane >> 4;

    const u16* gA[4]; const u16* gB[4];
    #pragma unroll
    for (int i = 0; i < 4; i++) {
        int c = i * 256 + tid;
        int r = c >> 3, kc = c & 7;
        int kcs = kc ^ (r & 7);
        int rid = sorted_rid[row0 + r];
        int tok = rid < 0 ? 0 : (rid >> 1);
        gA[i] = Xb + (size_t)tok * HD + kcs * 8;
        gB[i] = W1t + ((size_t)e * FD + (n0 + r)) * HD + kcs * 8;
    }
    char* AsB = (char*)As; char* BsB = (char*)Bs;

    f32x4 acc[4][4] = {};

    int wr = wave >> 1, wc = wave & 1;
    int off0 = ((kgrp ^ (lane & 7)) << 4);
    int off1 = off0 ^ 64;
    const char* Abase = AsB + (wr * 64 + laneR) * 128;
    const char* Bbase = BsB + (wc * 64 + laneR) * 128;

    for (int kt = 0; kt < HD / 64; kt++) {
        #pragma unroll
        for (int i = 0; i < 4; i++)
            GLOAD16(gA[i], AsB + i * 4096 + wave * 1024);
        #pragma unroll
        for (int i = 0; i < 4; i++)
            GLOAD16(gB[i], BsB + i * 4096 + wave * 1024);
        #pragma unroll
        for (int i = 0; i < 4; i++) { gA[i] += 64; gB[i] += 64; }
        __syncthreads();
        #pragma unroll
        for (int kk = 0; kk < 2; kk++) {
            int off = kk ? off1 : off0;
            bf16x8 a[4], b[4];
            #pragma unroll
            for (int m = 0; m < 4; m++) a[m] = *(const bf16x8*)(Abase + m * 2048 + off);
            #pragma unroll
            for (int n = 0; n < 4; n++) b[n] = *(const bf16x8*)(Bbase + n * 2048 + off);
            #pragma unroll
            for (int m = 0; m < 4; m++)
                #pragma unroll
                for (int n = 0; n < 4; n++)
                    acc[m][n] = __builtin_amdgcn_mfma_f32_16x16x32_bf16(b[n], a[m], acc[m][n], 0, 0, 0);
        }
        __syncthreads();
    }

    // epilogue (swapped layout): bias float4 + fixed gelu + cvt_pk + 8B stores
    const float* b1e = b1 + e * FD + n0;
    #pragma unroll
    for (int mf = 0; mf < 4; mf++) {
        int grow = row0 + wr * 64 + mf * 16 + laneR;
        u16* hrow = Hact + (size_t)grow * FD + n0;
        #pragma unroll
        for (int nf = 0; nf < 4; nf++) {
            int c = wc * 64 + nf * 16 + kgrp * 4;
            float4 bb = *(const float4*)(b1e + c);
            float g0 = gelu_f(acc[mf][nf][0] + bb.x);
            float g1 = gelu_f(acc[mf][nf][1] + bb.y);
            float g2 = gelu_f(acc[mf][nf][2] + bb.z);
            float g3 = gelu_f(acc[mf][nf][3] + bb.w);
            uint2 p = make_uint2(pk_bf16(g0, g1), pk_bf16(g2, g3));
            *(uint2*)(hrow + c) = p;
        }
    }
}

// ---------------- grouped GEMM 2: Out2[cslot] = H_act @ w2 + b2 (bf16, compacted) ----------------

__global__ __launch_bounds__(256, 2) void gemm2_kernel(
    const u16* __restrict__ Hact, const u16* __restrict__ W2t,
    const float* __restrict__ b2, const int* __restrict__ sorted_rid,
    const int* __restrict__ padcum,
    const int* __restrict__ tileE, const int* __restrict__ tileRow,
    const int* __restrict__ numTiles, u16* __restrict__ Out2)
{
    int bid = blockIdx.x;
    int xcd = bid & 7, slot = bid >> 3;
    int mt = xcd + (slot / NTN2) * 8;
    int n0 = (slot % NTN2) * 128;
    if (mt >= *numTiles) return;
    int e = tileE[mt];
    int row0 = tileRow[mt];

    __shared__ __align__(16) u16 As[128 * 64];
    __shared__ __align__(16) u16 Bs[128 * 64];

    int tid = threadIdx.x;
    int wave = tid >> 6, lane = tid & 63;
    int laneR = lane & 15, kgrp = lane >> 4;

    const u16* gA[4]; const u16* gB[4];
    #pragma unroll
    for (int i = 0; i < 4; i++) {
        int c = i * 256 + tid;
        int r = c >> 3, kc = c & 7;
        int kcs = kc ^ (r & 7);
        gA[i] = Hact + (size_t)(row0 + r) * FD + kcs * 8;
        gB[i] = W2t + ((size_t)e * HD + (n0 + r)) * FD + kcs * 8;
    }
    char* AsB = (char*)As; char* BsB = (char*)Bs;

    f32x4 acc[4][4] = {};

    int wr = wave >> 1, wc = wave & 1;
    int off0 = ((kgrp ^ (lane & 7)) << 4);
    int off1 = off0 ^ 64;
    const char* Abase = AsB + (wr * 64 + laneR) * 128;
    const char* Bbase = BsB + (wc * 64 + laneR) * 128;

    for (int kt = 0; kt < FD / 64; kt++) {
        #pragma unroll
        for (int i = 0; i < 4; i++)
            GLOAD16(gA[i], AsB + i * 4096 + wave * 1024);
        #pragma unroll
        for (int i = 0; i < 4; i++)
            GLOAD16(gB[i], BsB + i * 4096 + wave * 1024);
        #pragma unroll
        for (int i = 0; i < 4; i++) { gA[i] += 64; gB[i] += 64; }
        __syncthreads();
        #pragma unroll
        for (int kk = 0; kk < 2; kk++) {
            int off = kk ? off1 : off0;
            bf16x8 a[4], b[4];
            #pragma unroll
            for (int m = 0; m < 4; m++) a[m] = *(const bf16x8*)(Abase + m * 2048 + off);
            #pragma unroll
            for (int n = 0; n < 4; n++) b[n] = *(const bf16x8*)(Bbase + n * 2048 + off);
            #pragma unroll
            for (int m = 0; m < 4; m++)
                #pragma unroll
                for (int n = 0; n < 4; n++)
                    acc[m][n] = __builtin_amdgcn_mfma_f32_16x16x32_bf16(b[n], a[m], acc[m][n], 0, 0, 0);
        }
        __syncthreads();
    }

    // epilogue (swapped layout): 1 rid lookup per mf; cvt_pk + 8B stores
    const float* b2e = b2 + e * HD + n0;
    int pc = padcum[e];
    #pragma unroll
    for (int mf = 0; mf < 4; mf++) {
        int rr = row0 + wr * 64 + mf * 16 + laneR;
        int rid = sorted_rid[rr];
        if (rid < 0) continue;               // padding row: no storage
        u16* orow = Out2 + (size_t)(rr - pc) * HD + n0;
        #pragma unroll
        for (int nf = 0; nf < 4; nf++) {
            int c = wc * 64 + nf * 16 + kgrp * 4;
            float4 bb = *(const float4*)(b2e + c);
            float v0 = acc[mf][nf][0] + bb.x;
            float v1 = acc[mf][nf][1] + bb.y;
            float v2 = acc[mf][nf][2] + bb.z;
            float v3 = acc[mf][nf][3] + bb.w;
            uint2 p = make_uint2(pk_bf16(v0, v1), pk_bf16(v2, v3));
            *(uint2*)(orow + c) = p;
        }
    }
}

// ---------------- combine: y[t] = w0*Out2[inv[2t]] + w1*Out2[inv[2t+1]] ----------------

__global__ void combine_kernel(const u16* __restrict__ Out2, const int* __restrict__ inv,
                               const float* __restrict__ ew, float* __restrict__ y) {
    int i = blockIdx.x * blockDim.x + threadIdx.x;   // one thread = 8 cols of one token
    int tok = i >> 7;
    int c0 = (i & 127) << 3;
    int s0 = inv[2 * tok], s1 = inv[2 * tok + 1];
    float w0 = ew[2 * tok], w1 = ew[2 * tok + 1];
    union { uint4 v; u16 s[8]; } a, b;
    a.v = *(const uint4*)(Out2 + (size_t)s0 * HD + c0);
    b.v = *(const uint4*)(Out2 + (size_t)s1 * HD + c0);
    float out[8];
    #pragma unroll
    for (int j = 0; j < 8; j++) {
        union { u32 u; float f; } fa, fb;
        fa.u = (u32)a.s[j] << 16;
        fb.u = (u32)b.s[j] << 16;
        out[j] = w0 * fa.f + w1 * fb.f;
    }
    float4* yp = (float4*)(y + (size_t)tok * HD + c0);
    yp[0] = *(const float4*)&out[0];
    yp[1] = *(const float4*)&out[4];
}

// ---------------- launch ----------------

extern "C" void kernel_launch(void* const* d_in, const int* in_sizes, int n_in,
                              void* d_out, int out_size, void* d_ws, size_t ws_size,
                              hipStream_t stream) {
    const float* x  = (const float*)d_in[0];
    const float* ew = (const float*)d_in[1];
    const int*   te = (const int*)d_in[2];
    const float* w1 = (const float*)d_in[3];
    const float* b1 = (const float*)d_in[4];
    const float* w2 = (const float*)d_in[5];
    const float* b2 = (const float*)d_in[6];
    float* y = (float*)d_out;

    char* ws = (char*)d_ws;
    // Xb[0,32M) W1t[32M,64M) W2t[64M,96M) Hact[96M,228M) ip[228M+]
    // Out2 (compacted, 32768 x 1024 bf16 = 64MB) overlays Xb+W1t.
    u16* Xb   = (u16*)(ws);                      // 33,554,432 B
    u16* W1t  = (u16*)(ws + 33554432);           // 33,554,432 B
    u16* Out2 = (u16*)(ws);                      // 67,108,864 B (overlay)
    u16* W2t  = (u16*)(ws + 67108864);           // 33,554,432 B
    u16* Hact = (u16*)(ws + 100663296);          // 138,412,032 B (RP_MAX x 2048 bf16)
    char* ip  = ws + 239075328;
    int* numTiles = (int*)(ip);
    int* padcum   = (int*)(ip + 64);
    int* tileE    = (int*)(ip + 128);            // 1056 B
    int* tileRow  = (int*)(ip + 2048);           // 1056 B
    int* sorted   = (int*)(ip + 4096);           // 135,168 B
    int* inv      = (int*)(ip + 139264);         // 131,072 B

    // fused prep: convert_x | w1^T | w2^T | routing (last block)
    mega_prep<<<NB_PREP, 1024, 0, stream>>>(
        x, Xb, w1, W1t, w2, W2t, te, sorted, inv, tileE, tileRow, numTiles, padcum);

    // grouped GEMM 1
    gemm1_kernel<<<MAX_MT * NTN1, 256, 0, stream>>>(
        Xb, W1t, b1, sorted, tileE, tileRow, numTiles, Hact);

    // grouped GEMM 2 (compacted plain stores)
    gemm2_kernel<<<MAX_MT * NTN2, 256, 0, stream>>>(
        Hact, W2t, b2, sorted, padcum, tileE, tileRow, numTiles, Out2);

    // weighted topk combine
    combine_kernel<<<(TOKENS * 128) / 256, 256, 0, stream>>>(Out2, inv, ew, y);
}